// Round 2
// baseline (81.163 us; speedup 1.0000x reference)
//
#include <hip/hip_runtime.h>
#include <math.h>

#define NTOK 8192
#define DIMV 512
#define CD 13
#define KSZ 8192

#define SC_OFF (NTOK * CD * 4)          /* 425984: 4 scalar accumulators   */
#define C_OFF  (SC_OFF + 256)           /* 426240 (16B aligned): partial C */

// ---------------------------------------------------------------------------
// K1: h = x @ w_in + b_in (f64 accum), indices, commit & per-sample-entropy
//     partial sums, store h (f32) to ws.
// 16 lanes per token, 4 tokens per wave, 16 tokens per block.
// ---------------------------------------------------------------------------
__global__ __launch_bounds__(256) void k1_proj(const float* __restrict__ x,
                                               const float* __restrict__ w_in,
                                               const float* __restrict__ b_in,
                                               float* __restrict__ ws_h,
                                               float* __restrict__ ws_sc,
                                               float* __restrict__ out_ind) {
  __shared__ __align__(16) float s_winT[CD * DIMV];  // transposed [c][d]
  __shared__ float s_red[2];
  int t = threadIdx.x;
  if (t < 2) s_red[t] = 0.f;
  for (int g = t; g < CD * DIMV; g += 256) {
    int d = g / CD, c = g - d * CD;
    s_winT[c * DIMV + d] = w_in[g];
  }
  __syncthreads();

  int lane = t & 63;
  int wave = t >> 6;
  int l15 = lane & 15;
  int grp = lane >> 4;
  int n = blockIdx.x * 16 + wave * 4 + grp;

  const float4* x4 = (const float4*)(x + (size_t)n * DIMV);
  double acc[CD];
#pragma unroll
  for (int c = 0; c < CD; ++c) acc[c] = 0.0;

#pragma unroll
  for (int j = 0; j < 8; ++j) {
    float4 xv = x4[l15 + j * 16];
    int dbase = (l15 + j * 16) * 4;
#pragma unroll
    for (int c = 0; c < CD; ++c) {
      const float4 wv = *(const float4*)&s_winT[c * DIMV + dbase];
      acc[c] += (double)xv.x * wv.x + (double)xv.y * wv.y +
                (double)xv.z * wv.z + (double)xv.w * wv.w;
    }
  }
  // butterfly reduce within the 16-lane group; every lane gets all 13 h's
#pragma unroll
  for (int c = 0; c < CD; ++c) {
    acc[c] += __shfl_xor(acc[c], 1, 64);
    acc[c] += __shfl_xor(acc[c], 2, 64);
    acc[c] += __shfl_xor(acc[c], 4, 64);
    acc[c] += __shfl_xor(acc[c], 8, 64);
    acc[c] += (double)b_in[c];
  }

  if (l15 == 0) {
    int idx = 0;
#pragma unroll
    for (int c = 0; c < CD; ++c) idx |= (acc[c] > 0.0 ? 1 : 0) << (12 - c);
    out_ind[n] = (float)idx;
  }

  float cm = 0.f, pe = 0.f;
  if (l15 < CD) {
    float hv = (float)acc[l15];
    ws_h[(size_t)n * CD + l15] = hv;
    float a = fabsf(hv);
    float d1 = a - 1.f;
    cm = d1 * d1;                       // (h - sign(h))^2 == (|h|-1)^2
    float z = 4.f * a;                  // binary entropy of sigmoid(4h)
    float e = expf(-z);
    pe = log1pf(e) + z * e / (1.f + e);
  }
  cm += __shfl_xor(cm, 1, 64); pe += __shfl_xor(pe, 1, 64);
  cm += __shfl_xor(cm, 2, 64); pe += __shfl_xor(pe, 2, 64);
  cm += __shfl_xor(cm, 4, 64); pe += __shfl_xor(pe, 4, 64);
  cm += __shfl_xor(cm, 8, 64); pe += __shfl_xor(pe, 8, 64);
  if (l15 == 0) { atomicAdd(&s_red[0], cm); atomicAdd(&s_red[1], pe); }
  __syncthreads();
  if (t == 0) { atomicAdd(&ws_sc[0], s_red[0]); atomicAdd(&ws_sc[1], s_red[1]); }
}

// ---------------------------------------------------------------------------
// K1b: out = sign(h) @ w_out + b_out, signs unpacked from indices.
// One token per wave-iteration (whole wave covers 512 outputs), 16 tok/block.
// ---------------------------------------------------------------------------
__global__ __launch_bounds__(256) void k1b_out(const float* __restrict__ w_out,
                                               const float* __restrict__ b_out,
                                               const float* __restrict__ in_ind,
                                               float* __restrict__ outv) {
  __shared__ __align__(16) float s_wout[CD * DIMV];
  int t = threadIdx.x;
  for (int g = t; g < CD * DIMV; g += 256) s_wout[g] = w_out[g];
  __syncthreads();

  int lane = t & 63;
  int wave = t >> 6;
  int dpos = lane * 4;
  float4 b0 = *(const float4*)(b_out + dpos);
  float4 b1 = *(const float4*)(b_out + dpos + 256);
  int n0 = blockIdx.x * 16 + wave * 4;

  for (int tt = 0; tt < 4; ++tt) {
    int n = n0 + tt;
    int idx = (int)in_ind[n];
    float4 o0 = b0, o1 = b1;
#pragma unroll
    for (int c = 0; c < CD; ++c) {
      float sgn = ((idx >> (12 - c)) & 1) ? 1.f : -1.f;
      float4 w0 = *(const float4*)&s_wout[c * DIMV + dpos];
      float4 w1 = *(const float4*)&s_wout[c * DIMV + dpos + 256];
      o0.x = fmaf(sgn, w0.x, o0.x); o0.y = fmaf(sgn, w0.y, o0.y);
      o0.z = fmaf(sgn, w0.z, o0.z); o0.w = fmaf(sgn, w0.w, o0.w);
      o1.x = fmaf(sgn, w1.x, o1.x); o1.y = fmaf(sgn, w1.y, o1.y);
      o1.z = fmaf(sgn, w1.z, o1.z); o1.w = fmaf(sgn, w1.w, o1.w);
    }
    float4* dst = (float4*)(outv + (size_t)n * DIMV);
    dst[lane] = o0;
    dst[lane + 64] = o1;
  }
}

// ---------------------------------------------------------------------------
// K2: avg_probs via rank-1 factorization. probs[n] = A_n[64] (bits 0..5 of k)
//     outer B_n[128] (bits 6..12). Lane l owns khi=l row: acc[128].
//     Block-reduce 4 waves in LDS (transposed slot s = klo*64+khi), write
//     per-block partial to ws.  Entropy sum is permutation-invariant.
// All waves execute identical iteration counts (tokens_per_block % 4 == 0),
// so __syncthreads() inside the loop is safe and gives explicit LDS ordering.
// ---------------------------------------------------------------------------
__global__ __launch_bounds__(256) void k2_avgp(const float* __restrict__ ws_h,
                                               float* __restrict__ ws_C,
                                               int tokens_per_block) {
  __shared__ __align__(16) float sB[4][128];
  __shared__ __align__(16) float sC[KSZ];
  int t = threadIdx.x;
  int lane = t & 63;
  int wave = t >> 6;

  float acc[128];
#pragma unroll
  for (int i = 0; i < 128; ++i) acc[i] = 0.f;

  int n0 = blockIdx.x * tokens_per_block;
  for (int tt = wave; tt < tokens_per_block; tt += 4) {
    int n = n0 + tt;
    float p[CD], q[CD];
#pragma unroll
    for (int c = 0; c < CD; ++c) {
      float hv = ws_h[(size_t)n * CD + c];
      float e = expf(-4.f * hv);
      float r = 1.f / (1.f + e);
      p[c] = r;           // P(bit c = 1)
      q[c] = e * r;       // P(bit c = 0)
    }
    // A over c=0..5 (khi bit 5-c), lane = khi
    float A = ((lane >> 5) & 1) ? p[0] : q[0];
    A *= ((lane >> 4) & 1) ? p[1] : q[1];
    A *= ((lane >> 3) & 1) ? p[2] : q[2];
    A *= ((lane >> 2) & 1) ? p[3] : q[3];
    A *= ((lane >> 1) & 1) ? p[4] : q[4];
    A *= (lane & 1) ? p[5] : q[5];
    // B over c=7..12 (klo bit 12-c); c=6 is klo bit 6
    float Bb = ((lane >> 5) & 1) ? p[7] : q[7];
    Bb *= ((lane >> 4) & 1) ? p[8] : q[8];
    Bb *= ((lane >> 3) & 1) ? p[9] : q[9];
    Bb *= ((lane >> 2) & 1) ? p[10] : q[10];
    Bb *= ((lane >> 1) & 1) ? p[11] : q[11];
    Bb *= (lane & 1) ? p[12] : q[12];
    sB[wave][lane] = q[6] * Bb;        // klo = lane      (bit6 = 0)
    sB[wave][64 + lane] = p[6] * Bb;   // klo = lane + 64 (bit6 = 1)
    __syncthreads();                   // explicit LDS write->read ordering
    const float4* B4 = (const float4*)sB[wave];
#pragma unroll
    for (int kk = 0; kk < 32; ++kk) {
      float4 b = B4[kk];
      acc[kk * 4 + 0] = fmaf(A, b.x, acc[kk * 4 + 0]);
      acc[kk * 4 + 1] = fmaf(A, b.y, acc[kk * 4 + 1]);
      acc[kk * 4 + 2] = fmaf(A, b.z, acc[kk * 4 + 2]);
      acc[kk * 4 + 3] = fmaf(A, b.w, acc[kk * 4 + 3]);
    }
    __syncthreads();                   // protect sB before next-iter write
  }

  // block reduce: sC[klo*64 + khi]
  for (int w = 0; w < 4; ++w) {
    if (wave == w) {
#pragma unroll
      for (int i = 0; i < 128; ++i) {
        if (w == 0) sC[i * 64 + lane] = acc[i];
        else        sC[i * 64 + lane] += acc[i];
      }
    }
    __syncthreads();
  }
  float4* dst = (float4*)(ws_C + (size_t)blockIdx.x * KSZ);
  const float4* src = (const float4*)sC;
  for (int i = t; i < KSZ / 4; i += 256) dst[i] = src[i];
}

// ---------------------------------------------------------------------------
// K3: reduce nparts partial C's -> codebook entropy partial (atomic scalar).
// 256 blocks x 32 slots each; 8 partial-groups per block reduced in LDS.
// ---------------------------------------------------------------------------
__global__ __launch_bounds__(256) void k3_cbent(const float* __restrict__ ws_C,
                                                float* __restrict__ ws_sc,
                                                int nparts) {
  __shared__ float red[256];
  int t = threadIdx.x;
  int sl = t & 31, pg = t >> 5;
  int s = blockIdx.x * 32 + sl;
  float sum = 0.f;
  for (int p = pg; p < nparts; p += 8) sum += ws_C[(size_t)p * KSZ + s];
  red[t] = sum;
  __syncthreads();
  if (t < 32) {
    float v = red[t];
#pragma unroll
    for (int j = 1; j < 8; ++j) v += red[t + 32 * j];
    float avg = v * (1.f / (float)NTOK);
    float contrib = -avg * logf(avg + 1e-5f);
    contrib += __shfl_xor(contrib, 1, 64);
    contrib += __shfl_xor(contrib, 2, 64);
    contrib += __shfl_xor(contrib, 4, 64);
    contrib += __shfl_xor(contrib, 8, 64);
    contrib += __shfl_xor(contrib, 16, 64);
    if (t == 0) atomicAdd(&ws_sc[2], contrib);
  }
}

// ---------------------------------------------------------------------------
// K4: assemble aux_loss scalar.
// ---------------------------------------------------------------------------
__global__ void k4_final(const float* __restrict__ ws_sc,
                         float* __restrict__ d_aux) {
  float commit = ws_sc[0] * (1.f / (float)(NTOK * CD));
  float psE = ws_sc[1] * (1.f / (float)NTOK);
  float cbE = ws_sc[2];
  d_aux[0] = 0.1f * (psE - cbE) + 0.25f * commit;
}

extern "C" void kernel_launch(void* const* d_in, const int* in_sizes, int n_in,
                              void* d_out, int out_size, void* d_ws, size_t ws_size,
                              hipStream_t stream) {
  const float* x     = (const float*)d_in[0];
  const float* w_in  = (const float*)d_in[1];
  const float* b_in  = (const float*)d_in[2];
  const float* w_out = (const float*)d_in[3];
  const float* b_out = (const float*)d_in[4];
  // d_in[5] = codebook (unused: codes are the 13-bit sign patterns)

  float* outv = (float*)d_out;                       // [4*2048*512]
  float* ind  = outv + (size_t)NTOK * DIMV;          // [8192] as float
  float* aux  = ind + NTOK;                          // [1]

  float* ws_h  = (float*)d_ws;
  float* ws_sc = (float*)((char*)d_ws + SC_OFF);
  float* ws_C  = (float*)((char*)d_ws + C_OFF);

  int nparts = 256;
  while (nparts > 8 && (size_t)C_OFF + (size_t)nparts * KSZ * 4 > ws_size)
    nparts >>= 1;

  hipMemsetAsync(ws_sc, 0, 16, stream);
  k1_proj<<<NTOK / 16, 256, 0, stream>>>(x, w_in, b_in, ws_h, ws_sc, ind);
  k1b_out<<<NTOK / 16, 256, 0, stream>>>(w_out, b_out, ind, outv);
  k2_avgp<<<nparts, 256, 0, stream>>>(ws_h, ws_C, NTOK / nparts);
  k3_cbent<<<256, 256, 0, stream>>>(ws_C, ws_sc, nparts);
  k4_final<<<1, 1, 0, stream>>>(ws_sc, aux);
}